// Round 9
// baseline (201.265 us; speedup 1.0000x reference)
//
#include <hip/hip_runtime.h>
#include <stdint.h>

#define SEQ 2048
#define NTOK 4096          // B*S
#define DM 1024

typedef __bf16 bf16x8 __attribute__((ext_vector_type(8)));
typedef __bf16 bf16x4 __attribute__((ext_vector_type(4)));
typedef float f32x4 __attribute__((ext_vector_type(4)));

__device__ __forceinline__ unsigned short f2bf(float f) {
  union { float f; unsigned u; } v; v.f = f;
  return (unsigned short)((v.u + 0x7fffu + ((v.u >> 16) & 1u)) >> 16);
}
__device__ __forceinline__ float bf2f(unsigned short s) {
  union { unsigned u; float f; } v; v.u = ((unsigned)s) << 16; return v.f;
}
// pack two floats to packed bf16 (round-half-up) in ONE v_perm + 2 adds
__device__ __forceinline__ unsigned pkbf(float a, float b) {
  union { float f; unsigned u; } x, y; x.f = a; y.f = b;
  return __builtin_amdgcn_perm(y.u + 0x8000u, x.u + 0x8000u, 0x07060302u);
}

// async global->LDS, 16B per lane. LDS dest must be wave-uniform base + lane*16.
__device__ __forceinline__ void async16(const unsigned short* g, unsigned short* l) {
  __builtin_amdgcn_global_load_lds(
      (const __attribute__((address_space(1))) void*)g,
      (__attribute__((address_space(3))) void*)l, 16, 0, 0);
}

// one kernel casts x + all 4 weights (contiguous in ws)
__global__ __launch_bounds__(256) void cast_all(
    const float* __restrict__ x, const float* __restrict__ wq,
    const float* __restrict__ wk, const float* __restrict__ wv,
    const float* __restrict__ wo, unsigned short* __restrict__ dst) {
  size_t i = ((size_t)blockIdx.x * 256 + threadIdx.x) * 4;
  const float* src; size_t off;
  if (i < (size_t)NTOK * DM) { src = x; off = i; }
  else {
    size_t j = i - (size_t)NTOK * DM;
    int s = (int)(j >> 20);
    src = (s == 0) ? wq : (s == 1) ? wk : (s == 2) ? wv : wo;
    off = j & 1048575u;
  }
  float4 f = *(const float4*)(src + off);
  ushort4 o;
  o.x = f2bf(f.x); o.y = f2bf(f.y); o.z = f2bf(f.z); o.w = f2bf(f.w);
  *(ushort4*)(dst + i) = o;
}

// ---- Pipelined GEMM core (T3/T4-minimum): BK=32 half-K slices, 3 rotating
// LDS slots, global_load_lds prefetch issued 2 phases ahead, counted
// s_waitcnt vmcnt(N) fused with s_barrier (never 0 mid-loop).
// NOTE (R4 post-mortem): proven for 32-phase GEMMs (load-tail-exposed
// regime). REGRESSED flash-attn -- do not port it back there.

template<int MI>   // MI = A-frag rows/16 per wave pair; A-tile rows = MI*32
__device__ __forceinline__ void stage_half(
    const unsigned short* __restrict__ A, const unsigned short* __restrict__ Bw,
    int m0, int n0, int kt, unsigned short* As, unsigned short* Bs) {
  const int tid = threadIdx.x;
  const int r = tid >> 2, c = tid & 3;     // 64 rows x 4 chunks per 256 thr
#pragma unroll
  for (int b = 0; b < MI / 2; ++b) {
    const int row = b * 64 + r;
    async16(A + (size_t)(m0 + row) * 1024 + kt + ((c ^ (row & 3)) << 3),
            As + row * 32 + c * 8);        // dest = base + tid*16B (linear)
  }
#pragma unroll
  for (int b = 0; b < 2; ++b) {
    const int row = b * 64 + r;
    async16(Bw + (size_t)(n0 + row) * 1024 + kt + ((c ^ (row & 3)) << 3),
            Bs + row * 32 + c * 8);
  }
}

__device__ __forceinline__ void pipe_bar0() {
  asm volatile("s_waitcnt vmcnt(0)\ns_barrier" ::: "memory");
}
template<int MI>
__device__ __forceinline__ void pipe_barN() {
  // N = loads/thread/stage = MI/2 (A) + 2 (B): leave exactly the just-issued
  // stage in flight, guarantee the previous one has landed.
  if constexpr (MI == 4) asm volatile("s_waitcnt vmcnt(4)\ns_barrier" ::: "memory");
  else                   asm volatile("s_waitcnt vmcnt(3)\ns_barrier" ::: "memory");
}

template<int MI>
__device__ __forceinline__ void gemm_pipe(
    const unsigned short* __restrict__ A, const unsigned short* __restrict__ Bw,
    int m0, int n0, f32x4 (&acc)[MI][4],
    unsigned short* AsBase, unsigned short* BsBase) {
  const int tid = threadIdx.x, lane = tid & 63, w = tid >> 6;
  const int wm16 = (w >> 1) * MI * 16, wn = (w & 1) * 64;
  const int quad = lane >> 4, l16 = lane & 15;
  constexpr int ASZ = MI * 32 * 32;        // ushorts per A slot
  constexpr int BSZ = 128 * 32;            // ushorts per B slot

  // prologue: fill slots 0 and 1 (K-slices 0,1); wait slot0, keep slot1 flying
  stage_half<MI>(A, Bw, m0, n0, 0,  AsBase,       BsBase);
  stage_half<MI>(A, Bw, m0, n0, 32, AsBase + ASZ, BsBase + BSZ);
  pipe_barN<MI>();

  int cur = 0;
  for (int p = 0; p < 32; ++p) {           // 32 half-K phases cover K=1024
    const unsigned short* As = AsBase + cur * ASZ;
    const unsigned short* Bs = BsBase + cur * BSZ;

    // ds-reads of current slot first (feed MFMA asap)
    bf16x8 af[MI], bf[4];
    const int swz = ((quad ^ (l16 & 3)) << 3);
#pragma unroll
    for (int i = 0; i < MI; ++i)
      af[i] = *(const bf16x8*)(As + (wm16 + i * 16 + l16) * 32 + swz);
#pragma unroll
    for (int j = 0; j < 4; ++j)
      bf[j] = *(const bf16x8*)(Bs + (wn + j * 16 + l16) * 32 + swz);

    // prefetch slice p+2 into slot (cur+2)%3 (that slot's readers finished at
    // the end of phase p-1, so writes are race-free)
    if (p + 2 < 32) {
      const int slot = (cur == 0) ? 2 : cur - 1;
      stage_half<MI>(A, Bw, m0, n0, (p + 2) * 32,
                     AsBase + slot * ASZ, BsBase + slot * BSZ);
    }

#pragma unroll
    for (int i = 0; i < MI; ++i)
#pragma unroll
      for (int j = 0; j < 4; ++j)
        acc[i][j] = __builtin_amdgcn_mfma_f32_16x16x32_bf16(af[i], bf[j], acc[i][j], 0, 0, 0);

    if (p < 30)       pipe_barN<MI>();     // slice p+1 landed; p+2 in flight
    else if (p == 30) pipe_bar0();         // drain: slice 31 landed
    // p == 31: no barrier; epilogue is register-only
    cur = (cur == 2) ? 0 : cur + 1;
  }
}

// QKV projection. Pipelined core + R9 XCD-grouped decode: each XCD owns a
// 512-token slab of x (1 MB, L2-resident) for all 3 kinds.
// kind 0=Q (scaled log2e/8), 1=K, 2=V^T (A/B swapped for coalesced store).
__global__ __launch_bounds__(256, 3) void qkv_gemm(
    const unsigned short* __restrict__ xb,
    const unsigned short* __restrict__ wqb, const unsigned short* __restrict__ wkb,
    const unsigned short* __restrict__ wvb,
    const float* __restrict__ bq, const float* __restrict__ bk, const float* __restrict__ bv,
    unsigned short* __restrict__ Q, unsigned short* __restrict__ Kd,
    unsigned short* __restrict__ Vt) {
  __shared__ unsigned short As[3 * 128 * 32], Bs[3 * 128 * 32];   // 48 KB
  const int gx = blockIdx.x;
  const int kind = gx >> 8;
  const int rr = gx & 255;
  const int tok = 4 * (rr & 7) + ((rr >> 3) & 3);   // 0..31, XCD-grouped slabs
  const int oth = rr >> 5;                           // 0..7
  const unsigned short* A; const unsigned short* Bw;
  int m0, n0;
  if (kind == 2) { A = wvb; Bw = xb; m0 = oth * 128; n0 = tok * 128; }
  else { A = xb; Bw = kind ? wkb : wqb; m0 = tok * 128; n0 = oth * 128; }

  f32x4 acc[4][4];
#pragma unroll
  for (int i = 0; i < 4; ++i)
#pragma unroll
    for (int j = 0; j < 4; ++j) { f32x4 z = {0.f, 0.f, 0.f, 0.f}; acc[i][j] = z; }
  gemm_pipe<4>(A, Bw, m0, n0, acc, As, Bs);

  const int lane = threadIdx.x & 63, w = threadIdx.x >> 6;
  const int quad = lane >> 4, l16 = lane & 15;
  const int wm = (w >> 1) * 64, wn = (w & 1) * 64;

  if (kind == 2) {
    // m = channel, n = token
#pragma unroll
    for (int i = 0; i < 4; ++i)
#pragma unroll
      for (int j = 0; j < 4; ++j) {
        const int n = n0 + wn + j * 16 + l16;
        const int tb = n >> 11, s = n & 2047;
#pragma unroll
        for (int r = 0; r < 4; ++r) {
          const int m = m0 + wm + i * 16 + quad * 4 + r;
          const int h = m >> 6, d = m & 63;
          Vt[((size_t)(tb * 16 + h) * 64 + d) * SEQ + s] = f2bf(acc[i][j][r] + bv[m]);
        }
      }
  } else {
    const float* bias = (kind == 0) ? bq : bk;
    const float scale = (kind == 0) ? 0.180336880f : 1.0f;  // log2(e)/8 for Q
#pragma unroll
    for (int i = 0; i < 4; ++i)
#pragma unroll
    for (int j = 0; j < 4; ++j) {
        const int col = n0 + wn + j * 16 + l16;
        const float bb = bias[col];
        const int h = col >> 6, d = col & 63;
#pragma unroll
        for (int r = 0; r < 4; ++r) {
          const int m = m0 + wm + i * 16 + quad * 4 + r;
          const int b = m >> 11, s = m & 2047;
          const int bh = b * 16 + h;
          const unsigned short val = f2bf((acc[i][j][r] + bb) * scale);
          if (kind == 0) Q[((size_t)bh * SEQ + s) * 64 + d] = val;
          else           Kd[((size_t)bh * SEQ + s) * 64 + d] = val;
        }
      }
  }
}

// Flash attention, FUSED at qq=4 (R8). R7-vs-R6 A/B proved qq=4's DS economy
// is worth >=7us (16 b128 feed 72 MFMAs vs 36). 128-thread blocks (2 waves,
// each owning 64 q-rows) keep 2 independent blocks/CU for barrier decoupling:
// grid = 32 bh x 16 q-tiles = 512. Staging at 16-row granularity (row&15 =
// srow, so the proven g-swizzle algebra is unchanged). No Op/Lp/combine;
// normalize + Gram-Schmidt in the epilogue (cross-quad shfl reduce).
__global__ __launch_bounds__(128) void attn_kernel(
    const unsigned short* __restrict__ Q, const unsigned short* __restrict__ Kd,
    const unsigned short* __restrict__ Vt,
    unsigned short* __restrict__ O) {
  __shared__ unsigned short KV[4][4096];   // 32KB total
  const int gx = blockIdx.x;
  const int xcd = gx & 7;
  const int idx = gx >> 3;                 // 0..63
  const int bh  = xcd * 4 + (idx & 3);
  const int q0  = (idx >> 2) * 128;        // 0..15 -> q-tile base
  const int tid = threadIdx.x, lane = tid & 63, w = tid >> 6;   // w = 0,1
  const int quad = lane >> 4, l16 = lane & 15;
  const unsigned short* Qp = Q + (size_t)bh * SEQ * 64;
  const unsigned short* Kp = Kd + (size_t)bh * SEQ * 64;
  const unsigned short* Vp = Vt + (size_t)bh * 64 * SEQ;
  const int srow = tid >> 3;               // 0..15
  // g(r) = (r&3) | ((r&8)>>1): chunk c of row r stored at c ^ g(r)
  const int sc = ((tid & 7) ^ ((srow & 3) | ((srow & 8) >> 1))) << 3;

  // stage Q rows q0..q0+127 into KV[0..1] (16 rows per call, 8 calls)
#pragma unroll
  for (int c = 0; c < 8; ++c)
    async16(Qp + (size_t)(q0 + c * 16 + srow) * 64 + sc,
            KV[c >> 2] + (c & 3) * 1024 + tid * 8);
  __syncthreads();

  const int gl = (l16 & 3) | ((l16 & 8) >> 1);   // g(row) for rows with row&15==l16
  const int sel = l16 & 7;                       // g(R) for relabeled K rows
  // wave w owns q rows q0+64w..+63
  const unsigned short* Qsrc = KV[w];
  bf16x8 bQ[4][2];
#pragma unroll
  for (int qq = 0; qq < 4; ++qq) {
    const int qrow = qq * 16 + l16;
#pragma unroll
    for (int hh = 0; hh < 2; ++hh)
      bQ[qq][hh] = *(const bf16x8*)(Qsrc + qrow * 64 + (((hh * 4 + quad) ^ gl) << 3));
  }
  __syncthreads();   // all waves done reading Q before K0/V0 overwrite

  auto stageKV = [&](int kt, int nb) {
#pragma unroll
    for (int c = 0; c < 4; ++c)
      async16(Kp + (size_t)(kt + c * 16 + srow) * 64 + sc,
              KV[nb] + c * 1024 + tid * 8);
#pragma unroll
    for (int c = 0; c < 4; ++c)
      async16(Vp + (size_t)(c * 16 + srow) * SEQ + kt + sc,
              KV[2 + nb] + c * 1024 + tid * 8);
  };
  stageKV(0, 0);

  union { unsigned short u[8]; bf16x8 v; } one8;
#pragma unroll
  for (int t = 0; t < 8; ++t) one8.u[t] = 0x3F80;
  const bf16x8 aOnes = one8.v;

  f32x4 o_acc[4][4];
  f32x4 l_acc[4];
  const f32x4 zinit = {-12.f, -12.f, -12.f, -12.f};  // fixed softmax max
#pragma unroll
  for (int qq = 0; qq < 4; ++qq) {
    f32x4 z = {0.f, 0.f, 0.f, 0.f};
    l_acc[qq] = z;
#pragma unroll
    for (int dt = 0; dt < 4; ++dt) o_acc[qq][dt] = z;
  }

  for (int it = 0; it < 32; ++it) {
    const int cur = it & 1;
    __syncthreads();
    if (it + 1 < 32) stageKV((it + 1) * 64, (it + 1) & 1);
    const unsigned short* Ks = KV[cur];
    const unsigned short* Vs = KV[2 + cur];

    __builtin_amdgcn_s_setprio(1);   // T5: favor this wave through the MFMA mass

    // S^T - 12, P = schraudolph-exp2 packed to bf16 in 2 ops/element.
    // K-row relabel: MFMA (G,e) output row m holds K row 32G+8(m>>2)+4e+(m&3)
    // => bP[qq][G] element j at lane quad carries k-label 32G+8*quad+j.
    bf16x8 bP[4][2];
#pragma unroll
    for (int ee = 0; ee < 4; ++ee) {
      const int G = ee >> 1, e = ee & 1;
      const int R = G * 32 + ((l16 >> 2) << 3) + e * 4 + (l16 & 3);
      const unsigned short* arow = Ks + R * 64;
      bf16x8 a0 = *(const bf16x8*)(arow + ((quad ^ sel) << 3));
      bf16x8 a1 = *(const bf16x8*)(arow + (((4 + quad) ^ sel) << 3));
#pragma unroll
      for (int qq = 0; qq < 4; ++qq) {
        f32x4 z = __builtin_amdgcn_mfma_f32_16x16x32_bf16(a0, bQ[qq][0], zinit, 0, 0, 0);
        z = __builtin_amdgcn_mfma_f32_16x16x32_bf16(a1, bQ[qq][1], z, 0, 0, 0);
        const unsigned u0 = (unsigned)(int)__builtin_fmaf(z[0], 8388608.0f, 1065024977.0f);
        const unsigned u1 = (unsigned)(int)__builtin_fmaf(z[1], 8388608.0f, 1065024977.0f);
        const unsigned u2 = (unsigned)(int)__builtin_fmaf(z[2], 8388608.0f, 1065024977.0f);
        const unsigned u3 = (unsigned)(int)__builtin_fmaf(z[3], 8388608.0f, 1065024977.0f);
        union { unsigned d[4]; bf16x8 v; } pk;
        pk.v = bP[qq][G];
        pk.d[e * 2]     = __builtin_amdgcn_perm(u1, u0, 0x07060302u);
        pk.d[e * 2 + 1] = __builtin_amdgcn_perm(u3, u2, 0x07060302u);
        bP[qq][G] = pk.v;
      }
    }

    // denominator via ones-MFMA (all C rows identical = per-q sum)
#pragma unroll
    for (int qq = 0; qq < 4; ++qq)
#pragma unroll
      for (int G = 0; G < 2; ++G)
        l_acc[qq] = __builtin_amdgcn_mfma_f32_16x16x32_bf16(aOnes, bP[qq][G], l_acc[qq], 0, 0, 0);

    // O^T += Vt * P: single b128 V-frag per (dt,G), shared across 4 qq
#pragma unroll
    for (int dt = 0; dt < 4; ++dt) {
      const unsigned short* vbase = Vs + (dt * 16 + l16) * 64;
#pragma unroll
      for (int G = 0; G < 2; ++G) {
        bf16x8 aV = *(const bf16x8*)(vbase + (((G * 4 + quad) ^ gl) << 3));
#pragma unroll
        for (int qq = 0; qq < 4; ++qq)
          o_acc[qq][dt] = __builtin_amdgcn_mfma_f32_16x16x32_bf16(aV, bP[qq][G], o_acc[qq][dt], 0, 0, 0);
      }
    }

    __builtin_amdgcn_s_setprio(0);
  }

  // ---- epilogue: normalize + Gram-Schmidt exclusion + final store.
  const int b = bh >> 4, h = bh & 15;
#pragma unroll
  for (int qq = 0; qq < 4; ++qq) {
    const int qg = q0 + w * 64 + qq * 16 + l16;
    const float inv = 1.0f / l_acc[qq][0];
    const unsigned short* vp = Vp + qg;
    float ov = 0.f, v2 = 0.f;
#pragma unroll
    for (int dt = 0; dt < 4; ++dt)
#pragma unroll
      for (int r = 0; r < 4; ++r) {
        const int d = dt * 16 + quad * 4 + r;
        const float v = bf2f(vp[(size_t)d * SEQ]);
        ov += o_acc[qq][dt][r] * v;
        v2 += v * v;
      }
    ov *= inv;
    ov += __shfl_xor(ov, 16); ov += __shfl_xor(ov, 32);
    v2 += __shfl_xor(v2, 16); v2 += __shfl_xor(v2, 32);
    const float align = ov / (v2 + 1e-8f);
    unsigned short* dst = O + (size_t)(b * SEQ + qg) * DM + h * 64;
#pragma unroll
    for (int dt = 0; dt < 4; ++dt) {
      float a[4];
#pragma unroll
      for (int r = 0; r < 4; ++r) {
        const int d = dt * 16 + quad * 4 + r;
        const float v = bf2f(vp[(size_t)d * SEQ]);
        a[r] = __builtin_fmaf(o_acc[qq][dt][r], inv, -align * v);
      }
      uint2 pk2;
      pk2.x = pkbf(a[0], a[1]);
      pk2.y = pkbf(a[2], a[3]);
      *(uint2*)(dst + dt * 16 + quad * 4) = pk2;
    }
  }
}

// out = O @ Wo^T + bo, fp32 output. 128x128 tiles via gemm_pipe<4>.
__global__ __launch_bounds__(256, 3) void out_gemm(
    const unsigned short* __restrict__ Ob, const unsigned short* __restrict__ wob,
    const float* __restrict__ bo, float* __restrict__ out) {
  __shared__ unsigned short As[3 * 128 * 32], Bs[3 * 128 * 32];   // 48 KB
  const int m0 = blockIdx.y * 128, n0 = blockIdx.x * 128;
  f32x4 acc[4][4];
#pragma unroll
  for (int i = 0; i < 4; ++i)
#pragma unroll
    for (int j = 0; j < 4; ++j) { f32x4 z = {0.f, 0.f, 0.f, 0.f}; acc[i][j] = z; }

  gemm_pipe<4>(Ob, wob, m0, n0, acc, As, Bs);

  const int lane = threadIdx.x & 63, w = threadIdx.x >> 6;
  const int quad = lane >> 4, l16 = lane & 15;
  const int wm = (w >> 1) * 64, wn = (w & 1) * 64;
#pragma unroll
  for (int i = 0; i < 4; ++i)
#pragma unroll
    for (int j = 0; j < 4; ++j) {
      const int col = n0 + wn + j * 16 + l16;
      const float bb = bo[col];
#pragma unroll
      for (int r = 0; r < 4; ++r) {
        const int m = m0 + wm + i * 16 + quad * 4 + r;
        out[(size_t)m * DM + col] = acc[i][j][r] + bb;
      }
    }
}

extern "C" void kernel_launch(void* const* d_in, const int* in_sizes, int n_in,
                              void* d_out, int out_size, void* d_ws, size_t ws_size,
                              hipStream_t stream) {
  const float* x  = (const float*)d_in[0];
  const float* wq = (const float*)d_in[1];
  const float* bq = (const float*)d_in[2];
  const float* wk = (const float*)d_in[3];
  const float* bk = (const float*)d_in[4];
  const float* wv = (const float*)d_in[5];
  const float* bv = (const float*)d_in[6];
  const float* wo = (const float*)d_in[7];
  const float* bo = (const float*)d_in[8];
  float* out = (float*)d_out;
  (void)in_sizes; (void)n_in; (void)out_size; (void)ws_size;

  unsigned short* ws  = (unsigned short*)d_ws;
  unsigned short* xb  = ws;                         // 4096*1024
  unsigned short* wqb = xb + (size_t)NTOK * DM;     // 1024*1024 each (contiguous!)
  unsigned short* wkb = wqb + (size_t)DM * DM;
  unsigned short* wvb = wkb + (size_t)DM * DM;
  unsigned short* wob = wvb + (size_t)DM * DM;
  unsigned short* Qb  = wob + (size_t)DM * DM;      // [32][2048][64]
  unsigned short* Kb  = Qb + (size_t)NTOK * DM;
  unsigned short* Vtb = Kb + (size_t)NTOK * DM;     // [32][64][2048]
  unsigned short* Ob  = Vtb + (size_t)NTOK * DM;    // [4096][1024]

  cast_all<<<8192, 256, 0, stream>>>(x, wq, wk, wv, wo, ws);
  qkv_gemm<<<768, 256, 0, stream>>>(xb, wqb, wkb, wvb, bq, bk, bv, Qb, Kb, Vtb);
  attn_kernel<<<512, 128, 0, stream>>>(Qb, Kb, Vtb, Ob);
  out_gemm<<<dim3(8, 32), 256, 0, stream>>>(Ob, wob, bo, out);
}

// Round 10
// 177.863 us; speedup vs baseline: 1.1316x; 1.1316x over previous
//
#include <hip/hip_runtime.h>
#include <stdint.h>

#define SEQ 2048
#define NTOK 4096          // B*S
#define DM 1024

typedef __bf16 bf16x8 __attribute__((ext_vector_type(8)));
typedef __bf16 bf16x4 __attribute__((ext_vector_type(4)));
typedef float f32x4 __attribute__((ext_vector_type(4)));

__device__ __forceinline__ unsigned short f2bf(float f) {
  union { float f; unsigned u; } v; v.f = f;
  return (unsigned short)((v.u + 0x7fffu + ((v.u >> 16) & 1u)) >> 16);
}
__device__ __forceinline__ float bf2f(unsigned short s) {
  union { unsigned u; float f; } v; v.u = ((unsigned)s) << 16; return v.f;
}
// pack two floats to packed bf16 (round-half-up) in ONE v_perm + 2 adds
__device__ __forceinline__ unsigned pkbf(float a, float b) {
  union { float f; unsigned u; } x, y; x.f = a; y.f = b;
  return __builtin_amdgcn_perm(y.u + 0x8000u, x.u + 0x8000u, 0x07060302u);
}

// async global->LDS, 16B per lane. LDS dest must be wave-uniform base + lane*16.
__device__ __forceinline__ void async16(const unsigned short* g, unsigned short* l) {
  __builtin_amdgcn_global_load_lds(
      (const __attribute__((address_space(1))) void*)g,
      (__attribute__((address_space(3))) void*)l, 16, 0, 0);
}

// one kernel casts x + all 4 weights (contiguous in ws)
__global__ __launch_bounds__(256) void cast_all(
    const float* __restrict__ x, const float* __restrict__ wq,
    const float* __restrict__ wk, const float* __restrict__ wv,
    const float* __restrict__ wo, unsigned short* __restrict__ dst) {
  size_t i = ((size_t)blockIdx.x * 256 + threadIdx.x) * 4;
  const float* src; size_t off;
  if (i < (size_t)NTOK * DM) { src = x; off = i; }
  else {
    size_t j = i - (size_t)NTOK * DM;
    int s = (int)(j >> 20);
    src = (s == 0) ? wq : (s == 1) ? wk : (s == 2) ? wv : wo;
    off = j & 1048575u;
  }
  float4 f = *(const float4*)(src + off);
  ushort4 o;
  o.x = f2bf(f.x); o.y = f2bf(f.y); o.z = f2bf(f.z); o.w = f2bf(f.w);
  *(ushort4*)(dst + i) = o;
}

// ---- Pipelined GEMM core (T3/T4-minimum): BK=32 half-K slices, 3 rotating
// LDS slots, global_load_lds prefetch issued 2 phases ahead, counted
// s_waitcnt vmcnt(N) fused with s_barrier (never 0 mid-loop).
// NOTE (R4 post-mortem): proven for 32-phase GEMMs (load-tail-exposed
// regime). REGRESSED flash-attn -- do not port it back there.

template<int MI>   // MI = A-frag rows/16 per wave pair; A-tile rows = MI*32
__device__ __forceinline__ void stage_half(
    const unsigned short* __restrict__ A, const unsigned short* __restrict__ Bw,
    int m0, int n0, int kt, unsigned short* As, unsigned short* Bs) {
  const int tid = threadIdx.x;
  const int r = tid >> 2, c = tid & 3;     // 64 rows x 4 chunks per 256 thr
#pragma unroll
  for (int b = 0; b < MI / 2; ++b) {
    const int row = b * 64 + r;
    async16(A + (size_t)(m0 + row) * 1024 + kt + ((c ^ (row & 3)) << 3),
            As + row * 32 + c * 8);        // dest = base + tid*16B (linear)
  }
#pragma unroll
  for (int b = 0; b < 2; ++b) {
    const int row = b * 64 + r;
    async16(Bw + (size_t)(n0 + row) * 1024 + kt + ((c ^ (row & 3)) << 3),
            Bs + row * 32 + c * 8);
  }
}

__device__ __forceinline__ void pipe_bar0() {
  asm volatile("s_waitcnt vmcnt(0)\ns_barrier" ::: "memory");
}
template<int MI>
__device__ __forceinline__ void pipe_barN() {
  // N = loads/thread/stage = MI/2 (A) + 2 (B): leave exactly the just-issued
  // stage in flight, guarantee the previous one has landed.
  if constexpr (MI == 4) asm volatile("s_waitcnt vmcnt(4)\ns_barrier" ::: "memory");
  else                   asm volatile("s_waitcnt vmcnt(3)\ns_barrier" ::: "memory");
}

template<int MI>
__device__ __forceinline__ void gemm_pipe(
    const unsigned short* __restrict__ A, const unsigned short* __restrict__ Bw,
    int m0, int n0, f32x4 (&acc)[MI][4],
    unsigned short* AsBase, unsigned short* BsBase) {
  const int tid = threadIdx.x, lane = tid & 63, w = tid >> 6;
  const int wm16 = (w >> 1) * MI * 16, wn = (w & 1) * 64;
  const int quad = lane >> 4, l16 = lane & 15;
  constexpr int ASZ = MI * 32 * 32;        // ushorts per A slot
  constexpr int BSZ = 128 * 32;            // ushorts per B slot

  // prologue: fill slots 0 and 1 (K-slices 0,1); wait slot0, keep slot1 flying
  stage_half<MI>(A, Bw, m0, n0, 0,  AsBase,       BsBase);
  stage_half<MI>(A, Bw, m0, n0, 32, AsBase + ASZ, BsBase + BSZ);
  pipe_barN<MI>();

  int cur = 0;
  for (int p = 0; p < 32; ++p) {           // 32 half-K phases cover K=1024
    const unsigned short* As = AsBase + cur * ASZ;
    const unsigned short* Bs = BsBase + cur * BSZ;

    // ds-reads of current slot first (feed MFMA asap)
    bf16x8 af[MI], bf[4];
    const int swz = ((quad ^ (l16 & 3)) << 3);
#pragma unroll
    for (int i = 0; i < MI; ++i)
      af[i] = *(const bf16x8*)(As + (wm16 + i * 16 + l16) * 32 + swz);
#pragma unroll
    for (int j = 0; j < 4; ++j)
      bf[j] = *(const bf16x8*)(Bs + (wn + j * 16 + l16) * 32 + swz);

    // prefetch slice p+2 into slot (cur+2)%3 (that slot's readers finished at
    // the end of phase p-1, so writes are race-free)
    if (p + 2 < 32) {
      const int slot = (cur == 0) ? 2 : cur - 1;
      stage_half<MI>(A, Bw, m0, n0, (p + 2) * 32,
                     AsBase + slot * ASZ, BsBase + slot * BSZ);
    }

#pragma unroll
    for (int i = 0; i < MI; ++i)
#pragma unroll
      for (int j = 0; j < 4; ++j)
        acc[i][j] = __builtin_amdgcn_mfma_f32_16x16x32_bf16(af[i], bf[j], acc[i][j], 0, 0, 0);

    if (p < 30)       pipe_barN<MI>();     // slice p+1 landed; p+2 in flight
    else if (p == 30) pipe_bar0();         // drain: slice 31 landed
    // p == 31: no barrier; epilogue is register-only
    cur = (cur == 2) ? 0 : cur + 1;
  }
}

// QKV projection. Pipelined core + R9 XCD-grouped decode: each XCD owns a
// 512-token slab of x (1 MB, L2-resident) for all 3 kinds.
// kind 0=Q (scaled log2e/8), 1=K, 2=V^T (A/B swapped for coalesced store).
__global__ __launch_bounds__(256, 3) void qkv_gemm(
    const unsigned short* __restrict__ xb,
    const unsigned short* __restrict__ wqb, const unsigned short* __restrict__ wkb,
    const unsigned short* __restrict__ wvb,
    const float* __restrict__ bq, const float* __restrict__ bk, const float* __restrict__ bv,
    unsigned short* __restrict__ Q, unsigned short* __restrict__ Kd,
    unsigned short* __restrict__ Vt) {
  __shared__ unsigned short As[3 * 128 * 32], Bs[3 * 128 * 32];   // 48 KB
  const int gx = blockIdx.x;
  const int kind = gx >> 8;
  const int rr = gx & 255;
  const int tok = 4 * (rr & 7) + ((rr >> 3) & 3);   // 0..31, XCD-grouped slabs
  const int oth = rr >> 5;                           // 0..7
  const unsigned short* A; const unsigned short* Bw;
  int m0, n0;
  if (kind == 2) { A = wvb; Bw = xb; m0 = oth * 128; n0 = tok * 128; }
  else { A = xb; Bw = kind ? wkb : wqb; m0 = tok * 128; n0 = oth * 128; }

  f32x4 acc[4][4];
#pragma unroll
  for (int i = 0; i < 4; ++i)
#pragma unroll
    for (int j = 0; j < 4; ++j) { f32x4 z = {0.f, 0.f, 0.f, 0.f}; acc[i][j] = z; }
  gemm_pipe<4>(A, Bw, m0, n0, acc, As, Bs);

  const int lane = threadIdx.x & 63, w = threadIdx.x >> 6;
  const int quad = lane >> 4, l16 = lane & 15;
  const int wm = (w >> 1) * 64, wn = (w & 1) * 64;

  if (kind == 2) {
    // m = channel, n = token
#pragma unroll
    for (int i = 0; i < 4; ++i)
#pragma unroll
      for (int j = 0; j < 4; ++j) {
        const int n = n0 + wn + j * 16 + l16;
        const int tb = n >> 11, s = n & 2047;
#pragma unroll
        for (int r = 0; r < 4; ++r) {
          const int m = m0 + wm + i * 16 + quad * 4 + r;
          const int h = m >> 6, d = m & 63;
          Vt[((size_t)(tb * 16 + h) * 64 + d) * SEQ + s] = f2bf(acc[i][j][r] + bv[m]);
        }
      }
  } else {
    const float* bias = (kind == 0) ? bq : bk;
    const float scale = (kind == 0) ? 0.180336880f : 1.0f;  // log2(e)/8 for Q
#pragma unroll
    for (int i = 0; i < 4; ++i)
#pragma unroll
    for (int j = 0; j < 4; ++j) {
        const int col = n0 + wn + j * 16 + l16;
        const float bb = bias[col];
        const int h = col >> 6, d = col & 63;
#pragma unroll
        for (int r = 0; r < 4; ++r) {
          const int m = m0 + wm + i * 16 + quad * 4 + r;
          const int b = m >> 11, s = m & 2047;
          const int bh = b * 16 + h;
          const unsigned short val = f2bf((acc[i][j][r] + bb) * scale);
          if (kind == 0) Q[((size_t)bh * SEQ + s) * 64 + d] = val;
          else           Kd[((size_t)bh * SEQ + s) * 64 + d] = val;
        }
      }
  }
}

// Flash attention, FUSED with IN-BLOCK split-K (R10).
// Constraint set from R6..R9 A/Bs: need qq=4 DS economy (worth ~5-7us),
// fusion (worth ~10us), AND >=2 waves/SIMD (1 wave/SIMD = 69us, R9).
// Geometry: 256-thread blocks; waves {0,1} sweep keys 0..1023, waves {2,3}
// sweep keys 1024..2047; each wave owns 64 q-rows at qq=4, 16 iterations.
// Grid 512 (32 bh x 16 q-tiles of 128) = 2 blk/CU = 2 waves/SIMD.
// Partials combine INSIDE the block via one LDS exchange (no Op/Lp/combine).
// LDS 64KB: [K/V][kp][dbuf][4096] ushorts; 2 blk/CU -> 128KB of 160.
// Loop body = proven R6/R9 qq=4 algebra (relabel + g-swizzle + schraudolph
// + setprio). Epilogue: cross-pair LDS add, normalize, Gram-Schmidt, store.
__global__ __launch_bounds__(256, 2) void attn_kernel(
    const unsigned short* __restrict__ Q, const unsigned short* __restrict__ Kd,
    const unsigned short* __restrict__ Vt,
    unsigned short* __restrict__ O) {
  __shared__ unsigned short SH[32768];   // 64KB
  // K buffer for slice-group g, dbuf b; V likewise (each 8KB = 64 rows x 64)
#define KKB(g, b) (SH + ((g) * 2 + (b)) * 4096)
#define VVB(g, b) (SH + 16384 + ((g) * 2 + (b)) * 4096)
  const int gx = blockIdx.x;
  const int xcd = gx & 7;
  const int idx = gx >> 3;                 // 0..63
  const int bh  = xcd * 4 + (idx & 3);
  const int q0  = (idx >> 2) * 128;        // 0..15 -> q-tile base
  const int tid = threadIdx.x, lane = tid & 63, w = tid >> 6;   // w = 0..3
  const int kp = w >> 1;                   // key-slice group (0: keys 0..1023)
  const int wq = w & 1;                    // q-row half (owns q0+64*wq..+63)
  const int quad = lane >> 4, l16 = lane & 15;
  const unsigned short* Qp = Q + (size_t)bh * SEQ * 64;
  const unsigned short* Kp = Kd + (size_t)bh * SEQ * 64;
  const unsigned short* Vp = Vt + (size_t)bh * 64 * SEQ;
  const int srow = tid >> 3;               // 0..31
  // g(r) = (r&3) | ((r&8)>>1): chunk c of row r stored at c ^ g(r)
  const int sc = ((tid & 7) ^ ((srow & 3) | ((srow & 8) >> 1))) << 3;

  // stage Q rows q0..q0+127 into KKB(0,0) (rows 0-63) and KKB(0,1) (64-127)
#pragma unroll
  for (int c = 0; c < 4; ++c)
    async16(Qp + (size_t)(q0 + c * 32 + srow) * 64 + sc,
            KKB(0, c >> 1) + (c & 1) * 2048 + tid * 8);
  __syncthreads();

  const int gl = (l16 & 3) | ((l16 & 8) >> 1);   // g(row) for rows with row&15==l16
  const int sel = l16 & 7;                       // g(R) for relabeled K rows
  const unsigned short* Qsrc = KKB(0, wq);       // wave's 64 q-rows
  bf16x8 bQ[4][2];
#pragma unroll
  for (int qq = 0; qq < 4; ++qq) {
    const int qrow = qq * 16 + l16;
#pragma unroll
    for (int hh = 0; hh < 2; ++hh)
      bQ[qq][hh] = *(const bf16x8*)(Qsrc + qrow * 64 + (((hh * 4 + quad) ^ gl) << 3));
  }
  __syncthreads();   // all waves done reading Q before K0/V0 overwrite

  // stage both slice-groups' K/V tiles (8 async16/thread/iter)
  auto stageKV = [&](int it_, int nb) {
#pragma unroll
    for (int g = 0; g < 2; ++g) {
      const int kt = g * 1024 + it_ * 64;
      async16(Kp + (size_t)(kt + srow) * 64 + sc, KKB(g, nb) + tid * 8);
      async16(Kp + (size_t)(kt + 32 + srow) * 64 + sc, KKB(g, nb) + 2048 + tid * 8);
      async16(Vp + (size_t)srow * SEQ + kt + sc, VVB(g, nb) + tid * 8);
      async16(Vp + (size_t)(32 + srow) * SEQ + kt + sc, VVB(g, nb) + 2048 + tid * 8);
    }
  };
  stageKV(0, 0);

  union { unsigned short u[8]; bf16x8 v; } one8;
#pragma unroll
  for (int t = 0; t < 8; ++t) one8.u[t] = 0x3F80;
  const bf16x8 aOnes = one8.v;

  f32x4 o_acc[4][4];
  f32x4 l_acc[4];
  const f32x4 zinit = {-12.f, -12.f, -12.f, -12.f};  // fixed softmax max
#pragma unroll
  for (int qq = 0; qq < 4; ++qq) {
    f32x4 z = {0.f, 0.f, 0.f, 0.f};
    l_acc[qq] = z;
#pragma unroll
    for (int dt = 0; dt < 4; ++dt) o_acc[qq][dt] = z;
  }

  for (int it = 0; it < 16; ++it) {
    const int cur = it & 1;
    __syncthreads();
    if (it + 1 < 16) stageKV(it + 1, (it + 1) & 1);
    const unsigned short* Ks = KKB(kp, cur);
    const unsigned short* Vs = VVB(kp, cur);

    __builtin_amdgcn_s_setprio(1);   // T5: favor this wave through the MFMA mass

    // S^T - 12, P = schraudolph-exp2 packed to bf16 in 2 ops/element.
    // K-row relabel: MFMA (G,e) output row m holds K row 32G+8(m>>2)+4e+(m&3)
    // => bP[qq][G] element j at lane quad carries k-label 32G+8*quad+j.
    bf16x8 bP[4][2];
#pragma unroll
    for (int ee = 0; ee < 4; ++ee) {
      const int G = ee >> 1, e = ee & 1;
      const int R = G * 32 + ((l16 >> 2) << 3) + e * 4 + (l16 & 3);
      const unsigned short* arow = Ks + R * 64;
      bf16x8 a0 = *(const bf16x8*)(arow + ((quad ^ sel) << 3));
      bf16x8 a1 = *(const bf16x8*)(arow + (((4 + quad) ^ sel) << 3));
#pragma unroll
      for (int qq = 0; qq < 4; ++qq) {
        f32x4 z = __builtin_amdgcn_mfma_f32_16x16x32_bf16(a0, bQ[qq][0], zinit, 0, 0, 0);
        z = __builtin_amdgcn_mfma_f32_16x16x32_bf16(a1, bQ[qq][1], z, 0, 0, 0);
        const unsigned u0 = (unsigned)(int)__builtin_fmaf(z[0], 8388608.0f, 1065024977.0f);
        const unsigned u1 = (unsigned)(int)__builtin_fmaf(z[1], 8388608.0f, 1065024977.0f);
        const unsigned u2 = (unsigned)(int)__builtin_fmaf(z[2], 8388608.0f, 1065024977.0f);
        const unsigned u3 = (unsigned)(int)__builtin_fmaf(z[3], 8388608.0f, 1065024977.0f);
        union { unsigned d[4]; bf16x8 v; } pk;
        pk.v = bP[qq][G];
        pk.d[e * 2]     = __builtin_amdgcn_perm(u1, u0, 0x07060302u);
        pk.d[e * 2 + 1] = __builtin_amdgcn_perm(u3, u2, 0x07060302u);
        bP[qq][G] = pk.v;
      }
    }

    // denominator via ones-MFMA (all C rows identical = per-q sum)
#pragma unroll
    for (int qq = 0; qq < 4; ++qq)
#pragma unroll
      for (int G = 0; G < 2; ++G)
        l_acc[qq] = __builtin_amdgcn_mfma_f32_16x16x32_bf16(aOnes, bP[qq][G], l_acc[qq], 0, 0, 0);

    // O^T += Vt * P: single b128 V-frag per (dt,G), shared across 4 qq
#pragma unroll
    for (int dt = 0; dt < 4; ++dt) {
      const unsigned short* vbase = Vs + (dt * 16 + l16) * 64;
#pragma unroll
      for (int G = 0; G < 2; ++G) {
        bf16x8 aV = *(const bf16x8*)(vbase + (((G * 4 + quad) ^ gl) << 3));
#pragma unroll
        for (int qq = 0; qq < 4; ++qq)
          o_acc[qq][dt] = __builtin_amdgcn_mfma_f32_16x16x32_bf16(aV, bP[qq][G], o_acc[qq][dt], 0, 0, 0);
      }
    }

    __builtin_amdgcn_s_setprio(0);
  }

  // ---- cross-pair combine via LDS: waves kp==1 export (68 f32/lane,
  // stride 272B = 16B-aligned), waves kp==0 add. One-shot, conflicts minor.
  __syncthreads();   // all KV reads done; SH reusable
  float* xf = (float*)SH;
  if (kp == 1) {
    float* dst = xf + (size_t)(wq * 64 + lane) * 68;
#pragma unroll
    for (int qq = 0; qq < 4; ++qq)
#pragma unroll
      for (int dt = 0; dt < 4; ++dt)
        *(f32x4*)(dst + qq * 16 + dt * 4) = o_acc[qq][dt];
    f32x4 lv = {l_acc[0][0], l_acc[1][0], l_acc[2][0], l_acc[3][0]};
    *(f32x4*)(dst + 64) = lv;
  }
  __syncthreads();
  if (kp == 0) {
    const float* src = xf + (size_t)(wq * 64 + lane) * 68;
#pragma unroll
    for (int qq = 0; qq < 4; ++qq)
#pragma unroll
      for (int dt = 0; dt < 4; ++dt)
        o_acc[qq][dt] += *(const f32x4*)(src + qq * 16 + dt * 4);
    const f32x4 lv = *(const f32x4*)(src + 64);

    // ---- epilogue: normalize + Gram-Schmidt exclusion + final store.
    const int b = bh >> 4, h = bh & 15;
#pragma unroll
    for (int qq = 0; qq < 4; ++qq) {
      const int qg = q0 + wq * 64 + qq * 16 + l16;
      const float inv = 1.0f / (l_acc[qq][0] + lv[qq]);
      const unsigned short* vp = Vp + qg;
      float ov = 0.f, v2 = 0.f;
#pragma unroll
      for (int dt = 0; dt < 4; ++dt)
#pragma unroll
        for (int r = 0; r < 4; ++r) {
          const int d = dt * 16 + quad * 4 + r;
          const float v = bf2f(vp[(size_t)d * SEQ]);
          ov += o_acc[qq][dt][r] * v;
          v2 += v * v;
        }
      ov *= inv;
      ov += __shfl_xor(ov, 16); ov += __shfl_xor(ov, 32);
      v2 += __shfl_xor(v2, 16); v2 += __shfl_xor(v2, 32);
      const float align = ov / (v2 + 1e-8f);
      unsigned short* dst = O + (size_t)(b * SEQ + qg) * DM + h * 64;
#pragma unroll
      for (int dt = 0; dt < 4; ++dt) {
        float a[4];
#pragma unroll
        for (int r = 0; r < 4; ++r) {
          const int d = dt * 16 + quad * 4 + r;
          const float v = bf2f(vp[(size_t)d * SEQ]);
          a[r] = __builtin_fmaf(o_acc[qq][dt][r], inv, -align * v);
        }
        uint2 pk2;
        pk2.x = pkbf(a[0], a[1]);
        pk2.y = pkbf(a[2], a[3]);
        *(uint2*)(dst + dt * 16 + quad * 4) = pk2;
      }
    }
  }
#undef KKB
#undef VVB
}

// out = O @ Wo^T + bo, fp32 output. 128x128 tiles via gemm_pipe<4>.
__global__ __launch_bounds__(256, 3) void out_gemm(
    const unsigned short* __restrict__ Ob, const unsigned short* __restrict__ wob,
    const float* __restrict__ bo, float* __restrict__ out) {
  __shared__ unsigned short As[3 * 128 * 32], Bs[3 * 128 * 32];   // 48 KB
  const int m0 = blockIdx.y * 128, n0 = blockIdx.x * 128;
  f32x4 acc[4][4];
#pragma unroll
  for (int i = 0; i < 4; ++i)
#pragma unroll
    for (int j = 0; j < 4; ++j) { f32x4 z = {0.f, 0.f, 0.f, 0.f}; acc[i][j] = z; }

  gemm_pipe<4>(Ob, wob, m0, n0, acc, As, Bs);

  const int lane = threadIdx.x & 63, w = threadIdx.x >> 6;
  const int quad = lane >> 4, l16 = lane & 15;
  const int wm = (w >> 1) * 64, wn = (w & 1) * 64;
#pragma unroll
  for (int i = 0; i < 4; ++i)
#pragma unroll
    for (int j = 0; j < 4; ++j) {
      const int col = n0 + wn + j * 16 + l16;
      const float bb = bo[col];
#pragma unroll
      for (int r = 0; r < 4; ++r) {
        const int m = m0 + wm + i * 16 + quad * 4 + r;
        out[(size_t)m * DM + col] = acc[i][j][r] + bb;
      }
    }
}

extern "C" void kernel_launch(void* const* d_in, const int* in_sizes, int n_in,
                              void* d_out, int out_size, void* d_ws, size_t ws_size,
                              hipStream_t stream) {
  const float* x  = (const float*)d_in[0];
  const float* wq = (const float*)d_in[1];
  const float* bq = (const float*)d_in[2];
  const float* wk = (const float*)d_in[3];
  const float* bk = (const float*)d_in[4];
  const float* wv = (const float*)d_in[5];
  const float* bv = (const float*)d_in[6];
  const float* wo = (const float*)d_in[7];
  const float* bo = (const float*)d_in[8];
  float* out = (float*)d_out;
  (void)in_sizes; (void)n_in; (void)out_size; (void)ws_size;

  unsigned short* ws  = (unsigned short*)d_ws;
  unsigned short* xb  = ws;                         // 4096*1024
  unsigned short* wqb = xb + (size_t)NTOK * DM;     // 1024*1024 each (contiguous!)
  unsigned short* wkb = wqb + (size_t)DM * DM;
  unsigned short* wvb = wkb + (size_t)DM * DM;
  unsigned short* wob = wvb + (size_t)DM * DM;
  unsigned short* Qb  = wob + (size_t)DM * DM;      // [32][2048][64]
  unsigned short* Kb  = Qb + (size_t)NTOK * DM;
  unsigned short* Vtb = Kb + (size_t)NTOK * DM;     // [32][64][2048]
  unsigned short* Ob  = Vtb + (size_t)NTOK * DM;    // [4096][1024]

  cast_all<<<8192, 256, 0, stream>>>(x, wq, wk, wv, wo, ws);
  qkv_gemm<<<768, 256, 0, stream>>>(xb, wqb, wkb, wvb, bq, bk, bv, Qb, Kb, Vtb);
  attn_kernel<<<512, 256, 0, stream>>>(Qb, Kb, Vtb, Ob);
  out_gemm<<<dim3(8, 32), 256, 0, stream>>>(Ob, wob, bo, out);
}

// Round 11
// 177.680 us; speedup vs baseline: 1.1327x; 1.0010x over previous
//
#include <hip/hip_runtime.h>
#include <stdint.h>

#define SEQ 2048
#define NTOK 4096          // B*S
#define DM 1024

typedef __bf16 bf16x8 __attribute__((ext_vector_type(8)));
typedef __bf16 bf16x4 __attribute__((ext_vector_type(4)));
typedef float f32x4 __attribute__((ext_vector_type(4)));

__device__ __forceinline__ unsigned short f2bf(float f) {
  union { float f; unsigned u; } v; v.f = f;
  return (unsigned short)((v.u + 0x7fffu + ((v.u >> 16) & 1u)) >> 16);
}
__device__ __forceinline__ float bf2f(unsigned short s) {
  union { unsigned u; float f; } v; v.u = ((unsigned)s) << 16; return v.f;
}
// pack two floats to packed bf16 (round-half-up) in ONE v_perm + 2 adds
__device__ __forceinline__ unsigned pkbf(float a, float b) {
  union { float f; unsigned u; } x, y; x.f = a; y.f = b;
  return __builtin_amdgcn_perm(y.u + 0x8000u, x.u + 0x8000u, 0x07060302u);
}

// async global->LDS, 16B per lane. LDS dest must be wave-uniform base + lane*16.
__device__ __forceinline__ void async16(const unsigned short* g, unsigned short* l) {
  __builtin_amdgcn_global_load_lds(
      (const __attribute__((address_space(1))) void*)g,
      (__attribute__((address_space(3))) void*)l, 16, 0, 0);
}

// one kernel casts x + all 4 weights (contiguous in ws)
__global__ __launch_bounds__(256) void cast_all(
    const float* __restrict__ x, const float* __restrict__ wq,
    const float* __restrict__ wk, const float* __restrict__ wv,
    const float* __restrict__ wo, unsigned short* __restrict__ dst) {
  size_t i = ((size_t)blockIdx.x * 256 + threadIdx.x) * 4;
  const float* src; size_t off;
  if (i < (size_t)NTOK * DM) { src = x; off = i; }
  else {
    size_t j = i - (size_t)NTOK * DM;
    int s = (int)(j >> 20);
    src = (s == 0) ? wq : (s == 1) ? wk : (s == 2) ? wv : wo;
    off = j & 1048575u;
  }
  float4 f = *(const float4*)(src + off);
  ushort4 o;
  o.x = f2bf(f.x); o.y = f2bf(f.y); o.z = f2bf(f.z); o.w = f2bf(f.w);
  *(ushort4*)(dst + i) = o;
}

// ---- Pipelined GEMM core (T3/T4-minimum): BK=32 half-K slices, 3 rotating
// LDS slots, global_load_lds prefetch issued 2 phases ahead, counted
// s_waitcnt vmcnt(N) fused with s_barrier (never 0 mid-loop).
// NOTE (R4 post-mortem): proven for 32-phase GEMMs (load-tail-exposed
// regime). REGRESSED flash-attn -- do not port it back there.

template<int MI>   // MI = A-frag rows/16 per wave pair; A-tile rows = MI*32
__device__ __forceinline__ void stage_half(
    const unsigned short* __restrict__ A, const unsigned short* __restrict__ Bw,
    int m0, int n0, int kt, unsigned short* As, unsigned short* Bs) {
  const int tid = threadIdx.x;
  const int r = tid >> 2, c = tid & 3;     // 64 rows x 4 chunks per 256 thr
#pragma unroll
  for (int b = 0; b < MI / 2; ++b) {
    const int row = b * 64 + r;
    async16(A + (size_t)(m0 + row) * 1024 + kt + ((c ^ (row & 3)) << 3),
            As + row * 32 + c * 8);        // dest = base + tid*16B (linear)
  }
#pragma unroll
  for (int b = 0; b < 2; ++b) {
    const int row = b * 64 + r;
    async16(Bw + (size_t)(n0 + row) * 1024 + kt + ((c ^ (row & 3)) << 3),
            Bs + row * 32 + c * 8);
  }
}

__device__ __forceinline__ void pipe_bar0() {
  asm volatile("s_waitcnt vmcnt(0)\ns_barrier" ::: "memory");
}
template<int MI>
__device__ __forceinline__ void pipe_barN() {
  // N = loads/thread/stage = MI/2 (A) + 2 (B): leave exactly the just-issued
  // stage in flight, guarantee the previous one has landed.
  if constexpr (MI == 4) asm volatile("s_waitcnt vmcnt(4)\ns_barrier" ::: "memory");
  else                   asm volatile("s_waitcnt vmcnt(3)\ns_barrier" ::: "memory");
}

template<int MI>
__device__ __forceinline__ void gemm_pipe(
    const unsigned short* __restrict__ A, const unsigned short* __restrict__ Bw,
    int m0, int n0, f32x4 (&acc)[MI][4],
    unsigned short* AsBase, unsigned short* BsBase) {
  const int tid = threadIdx.x, lane = tid & 63, w = tid >> 6;
  const int wm16 = (w >> 1) * MI * 16, wn = (w & 1) * 64;
  const int quad = lane >> 4, l16 = lane & 15;
  constexpr int ASZ = MI * 32 * 32;        // ushorts per A slot
  constexpr int BSZ = 128 * 32;            // ushorts per B slot

  // prologue: fill slots 0 and 1 (K-slices 0,1); wait slot0, keep slot1 flying
  stage_half<MI>(A, Bw, m0, n0, 0,  AsBase,       BsBase);
  stage_half<MI>(A, Bw, m0, n0, 32, AsBase + ASZ, BsBase + BSZ);
  pipe_barN<MI>();

  int cur = 0;
  for (int p = 0; p < 32; ++p) {           // 32 half-K phases cover K=1024
    const unsigned short* As = AsBase + cur * ASZ;
    const unsigned short* Bs = BsBase + cur * BSZ;

    // ds-reads of current slot first (feed MFMA asap)
    bf16x8 af[MI], bf[4];
    const int swz = ((quad ^ (l16 & 3)) << 3);
#pragma unroll
    for (int i = 0; i < MI; ++i)
      af[i] = *(const bf16x8*)(As + (wm16 + i * 16 + l16) * 32 + swz);
#pragma unroll
    for (int j = 0; j < 4; ++j)
      bf[j] = *(const bf16x8*)(Bs + (wn + j * 16 + l16) * 32 + swz);

    // prefetch slice p+2 into slot (cur+2)%3 (that slot's readers finished at
    // the end of phase p-1, so writes are race-free)
    if (p + 2 < 32) {
      const int slot = (cur == 0) ? 2 : cur - 1;
      stage_half<MI>(A, Bw, m0, n0, (p + 2) * 32,
                     AsBase + slot * ASZ, BsBase + slot * BSZ);
    }

#pragma unroll
    for (int i = 0; i < MI; ++i)
#pragma unroll
      for (int j = 0; j < 4; ++j)
        acc[i][j] = __builtin_amdgcn_mfma_f32_16x16x32_bf16(af[i], bf[j], acc[i][j], 0, 0, 0);

    if (p < 30)       pipe_barN<MI>();     // slice p+1 landed; p+2 in flight
    else if (p == 30) pipe_bar0();         // drain: slice 31 landed
    // p == 31: no barrier; epilogue is register-only
    cur = (cur == 2) ? 0 : cur + 1;
  }
}

// ---- R11: fused Q+K pipe. Shared A-tile (x slab), two B-tiles (wq, wk),
// two accumulators. Stage = 6 loads/thread (A2+Bq2+Bk2) -> vmcnt(6).
// Stage bytes/MFMA drops 256 -> 187; x L2-reads halved.
__device__ __forceinline__ void stage_half_qk(
    const unsigned short* __restrict__ A, const unsigned short* __restrict__ Bq,
    const unsigned short* __restrict__ Bk,
    int m0, int n0, int kt, unsigned short* As, unsigned short* Bqs,
    unsigned short* Bks) {
  const int tid = threadIdx.x;
  const int r = tid >> 2, c = tid & 3;
#pragma unroll
  for (int b = 0; b < 2; ++b) {
    const int row = b * 64 + r;
    const int off = kt + ((c ^ (row & 3)) << 3);
    async16(A + (size_t)(m0 + row) * 1024 + off, As + row * 32 + c * 8);
    async16(Bq + (size_t)(n0 + row) * 1024 + off, Bqs + row * 32 + c * 8);
    async16(Bk + (size_t)(n0 + row) * 1024 + off, Bks + row * 32 + c * 8);
  }
}
__device__ __forceinline__ void pipe_barQK() {
  asm volatile("s_waitcnt vmcnt(6)\ns_barrier" ::: "memory");
}

__device__ __forceinline__ void gemm_pipe_qk(
    const unsigned short* __restrict__ A, const unsigned short* __restrict__ Bq,
    const unsigned short* __restrict__ Bk,
    int m0, int n0, f32x4 (&accQ)[4][4], f32x4 (&accK)[4][4],
    unsigned short* AsBase, unsigned short* BqBase, unsigned short* BkBase) {
  const int tid = threadIdx.x, lane = tid & 63, w = tid >> 6;
  const int wm16 = (w >> 1) * 64, wn = (w & 1) * 64;
  const int quad = lane >> 4, l16 = lane & 15;
  constexpr int SZ = 128 * 32;             // ushorts per slot (all three)

  stage_half_qk(A, Bq, Bk, m0, n0, 0,  AsBase,      BqBase,      BkBase);
  stage_half_qk(A, Bq, Bk, m0, n0, 32, AsBase + SZ, BqBase + SZ, BkBase + SZ);
  pipe_barQK();

  int cur = 0;
  for (int p = 0; p < 32; ++p) {
    const unsigned short* As = AsBase + cur * SZ;
    const unsigned short* Bqs = BqBase + cur * SZ;
    const unsigned short* Bks = BkBase + cur * SZ;

    bf16x8 af[4], bq[4], bk[4];
    const int swz = ((quad ^ (l16 & 3)) << 3);
#pragma unroll
    for (int i = 0; i < 4; ++i)
      af[i] = *(const bf16x8*)(As + (wm16 + i * 16 + l16) * 32 + swz);
#pragma unroll
    for (int j = 0; j < 4; ++j) {
      bq[j] = *(const bf16x8*)(Bqs + (wn + j * 16 + l16) * 32 + swz);
      bk[j] = *(const bf16x8*)(Bks + (wn + j * 16 + l16) * 32 + swz);
    }

    if (p + 2 < 32) {
      const int slot = (cur == 0) ? 2 : cur - 1;
      stage_half_qk(A, Bq, Bk, m0, n0, (p + 2) * 32,
                    AsBase + slot * SZ, BqBase + slot * SZ, BkBase + slot * SZ);
    }

#pragma unroll
    for (int i = 0; i < 4; ++i)
#pragma unroll
      for (int j = 0; j < 4; ++j) {
        accQ[i][j] = __builtin_amdgcn_mfma_f32_16x16x32_bf16(af[i], bq[j], accQ[i][j], 0, 0, 0);
        accK[i][j] = __builtin_amdgcn_mfma_f32_16x16x32_bf16(af[i], bk[j], accK[i][j], 0, 0, 0);
      }

    if (p < 30)       pipe_barQK();
    else if (p == 30) pipe_bar0();
    cur = (cur == 2) ? 0 : cur + 1;
  }
}

// QKV projection (R11): 512 blocks = one fully-resident round at 2 blk/CU.
// gx<256: fused Q+K block (shared x A-tile); gx>=256: V^T block (old path).
// XCD-grouped decode retained (tok slabs L2-resident per XCD).
__global__ __launch_bounds__(256, 2) void qkv_gemm(
    const unsigned short* __restrict__ xb,
    const unsigned short* __restrict__ wqb, const unsigned short* __restrict__ wkb,
    const unsigned short* __restrict__ wvb,
    const float* __restrict__ bq, const float* __restrict__ bk, const float* __restrict__ bv,
    unsigned short* __restrict__ Q, unsigned short* __restrict__ Kd,
    unsigned short* __restrict__ Vt) {
  __shared__ unsigned short SH[9 * 128 * 32];   // 72 KB (3 arrays x 3 slots)
  const int gx = blockIdx.x;
  const int rr = gx & 255;
  const int tok = 4 * (rr & 7) + ((rr >> 3) & 3);   // 0..31, XCD-grouped slabs
  const int oth = rr >> 5;                           // 0..7
  const int lane = threadIdx.x & 63, w = threadIdx.x >> 6;
  const int quad = lane >> 4, l16 = lane & 15;
  const int wm = (w >> 1) * 64, wn = (w & 1) * 64;

  if (gx < 256) {
    // ---- fused Q+K: A = x slab, Bq = wq, Bk = wk
    const int m0 = tok * 128, n0 = oth * 128;
    f32x4 accQ[4][4], accK[4][4];
#pragma unroll
    for (int i = 0; i < 4; ++i)
#pragma unroll
      for (int j = 0; j < 4; ++j) {
        f32x4 z = {0.f, 0.f, 0.f, 0.f};
        accQ[i][j] = z; accK[i][j] = z;
      }
    gemm_pipe_qk(xb, wqb, wkb, m0, n0, accQ, accK,
                 SH, SH + 3 * 4096, SH + 6 * 4096);

#pragma unroll
    for (int i = 0; i < 4; ++i)
#pragma unroll
      for (int j = 0; j < 4; ++j) {
        const int col = n0 + wn + j * 16 + l16;
        const float bbq = bq[col], bbk = bk[col];
        const int h = col >> 6, d = col & 63;
#pragma unroll
        for (int r = 0; r < 4; ++r) {
          const int m = m0 + wm + i * 16 + quad * 4 + r;
          const int b = m >> 11, s = m & 2047;
          const int bh = b * 16 + h;
          Q[((size_t)bh * SEQ + s) * 64 + d] =
              f2bf((accQ[i][j][r] + bbq) * 0.180336880f);   // log2(e)/8
          Kd[((size_t)bh * SEQ + s) * 64 + d] = f2bf(accK[i][j][r] + bbk);
        }
      }
  } else {
    // ---- V^T: A = wv (channels), B = x slab; coalesced [ch][token] store
    const int m0 = oth * 128, n0 = tok * 128;
    f32x4 acc[4][4];
#pragma unroll
    for (int i = 0; i < 4; ++i)
#pragma unroll
      for (int j = 0; j < 4; ++j) { f32x4 z = {0.f, 0.f, 0.f, 0.f}; acc[i][j] = z; }
    gemm_pipe<4>(wvb, xb, m0, n0, acc, SH, SH + 3 * 4096);

#pragma unroll
    for (int i = 0; i < 4; ++i)
#pragma unroll
      for (int j = 0; j < 4; ++j) {
        const int n = n0 + wn + j * 16 + l16;
        const int tb = n >> 11, s = n & 2047;
#pragma unroll
        for (int r = 0; r < 4; ++r) {
          const int m = m0 + wm + i * 16 + quad * 4 + r;
          const int h = m >> 6, d = m & 63;
          Vt[((size_t)(tb * 16 + h) * 64 + d) * SEQ + s] = f2bf(acc[i][j][r] + bv[m]);
        }
      }
  }
}

// Flash attention, FUSED with IN-BLOCK split-K (R10, unchanged).
__global__ __launch_bounds__(256, 2) void attn_kernel(
    const unsigned short* __restrict__ Q, const unsigned short* __restrict__ Kd,
    const unsigned short* __restrict__ Vt,
    unsigned short* __restrict__ O) {
  __shared__ unsigned short SH[32768];   // 64KB
#define KKB(g, b) (SH + ((g) * 2 + (b)) * 4096)
#define VVB(g, b) (SH + 16384 + ((g) * 2 + (b)) * 4096)
  const int gx = blockIdx.x;
  const int xcd = gx & 7;
  const int idx = gx >> 3;                 // 0..63
  const int bh  = xcd * 4 + (idx & 3);
  const int q0  = (idx >> 2) * 128;        // 0..15 -> q-tile base
  const int tid = threadIdx.x, lane = tid & 63, w = tid >> 6;   // w = 0..3
  const int kp = w >> 1;                   // key-slice group (0: keys 0..1023)
  const int wq = w & 1;                    // q-row half (owns q0+64*wq..+63)
  const int quad = lane >> 4, l16 = lane & 15;
  const unsigned short* Qp = Q + (size_t)bh * SEQ * 64;
  const unsigned short* Kp = Kd + (size_t)bh * SEQ * 64;
  const unsigned short* Vp = Vt + (size_t)bh * 64 * SEQ;
  const int srow = tid >> 3;               // 0..31
  const int sc = ((tid & 7) ^ ((srow & 3) | ((srow & 8) >> 1))) << 3;

  // stage Q rows q0..q0+127 into KKB(0,0) (rows 0-63) and KKB(0,1) (64-127)
#pragma unroll
  for (int c = 0; c < 4; ++c)
    async16(Qp + (size_t)(q0 + c * 32 + srow) * 64 + sc,
            KKB(0, c >> 1) + (c & 1) * 2048 + tid * 8);
  __syncthreads();

  const int gl = (l16 & 3) | ((l16 & 8) >> 1);   // g(row) for rows with row&15==l16
  const int sel = l16 & 7;                       // g(R) for relabeled K rows
  const unsigned short* Qsrc = KKB(0, wq);       // wave's 64 q-rows
  bf16x8 bQ[4][2];
#pragma unroll
  for (int qq = 0; qq < 4; ++qq) {
    const int qrow = qq * 16 + l16;
#pragma unroll
    for (int hh = 0; hh < 2; ++hh)
      bQ[qq][hh] = *(const bf16x8*)(Qsrc + qrow * 64 + (((hh * 4 + quad) ^ gl) << 3));
  }
  __syncthreads();   // all waves done reading Q before K0/V0 overwrite

  auto stageKV = [&](int it_, int nb) {
#pragma unroll
    for (int g = 0; g < 2; ++g) {
      const int kt = g * 1024 + it_ * 64;
      async16(Kp + (size_t)(kt + srow) * 64 + sc, KKB(g, nb) + tid * 8);
      async16(Kp + (size_t)(kt + 32 + srow) * 64 + sc, KKB(g, nb) + 2048 + tid * 8);
      async16(Vp + (size_t)srow * SEQ + kt + sc, VVB(g, nb) + tid * 8);
      async16(Vp + (size_t)(32 + srow) * SEQ + kt + sc, VVB(g, nb) + 2048 + tid * 8);
    }
  };
  stageKV(0, 0);

  union { unsigned short u[8]; bf16x8 v; } one8;
#pragma unroll
  for (int t = 0; t < 8; ++t) one8.u[t] = 0x3F80;
  const bf16x8 aOnes = one8.v;

  f32x4 o_acc[4][4];
  f32x4 l_acc[4];
  const f32x4 zinit = {-12.f, -12.f, -12.f, -12.f};  // fixed softmax max
#pragma unroll
  for (int qq = 0; qq < 4; ++qq) {
    f32x4 z = {0.f, 0.f, 0.f, 0.f};
    l_acc[qq] = z;
#pragma unroll
    for (int dt = 0; dt < 4; ++dt) o_acc[qq][dt] = z;
  }

  for (int it = 0; it < 16; ++it) {
    const int cur = it & 1;
    __syncthreads();
    if (it + 1 < 16) stageKV(it + 1, (it + 1) & 1);
    const unsigned short* Ks = KKB(kp, cur);
    const unsigned short* Vs = VVB(kp, cur);

    __builtin_amdgcn_s_setprio(1);   // T5

    bf16x8 bP[4][2];
#pragma unroll
    for (int ee = 0; ee < 4; ++ee) {
      const int G = ee >> 1, e = ee & 1;
      const int R = G * 32 + ((l16 >> 2) << 3) + e * 4 + (l16 & 3);
      const unsigned short* arow = Ks + R * 64;
      bf16x8 a0 = *(const bf16x8*)(arow + ((quad ^ sel) << 3));
      bf16x8 a1 = *(const bf16x8*)(arow + (((4 + quad) ^ sel) << 3));
#pragma unroll
      for (int qq = 0; qq < 4; ++qq) {
        f32x4 z = __builtin_amdgcn_mfma_f32_16x16x32_bf16(a0, bQ[qq][0], zinit, 0, 0, 0);
        z = __builtin_amdgcn_mfma_f32_16x16x32_bf16(a1, bQ[qq][1], z, 0, 0, 0);
        const unsigned u0 = (unsigned)(int)__builtin_fmaf(z[0], 8388608.0f, 1065024977.0f);
        const unsigned u1 = (unsigned)(int)__builtin_fmaf(z[1], 8388608.0f, 1065024977.0f);
        const unsigned u2 = (unsigned)(int)__builtin_fmaf(z[2], 8388608.0f, 1065024977.0f);
        const unsigned u3 = (unsigned)(int)__builtin_fmaf(z[3], 8388608.0f, 1065024977.0f);
        union { unsigned d[4]; bf16x8 v; } pk;
        pk.v = bP[qq][G];
        pk.d[e * 2]     = __builtin_amdgcn_perm(u1, u0, 0x07060302u);
        pk.d[e * 2 + 1] = __builtin_amdgcn_perm(u3, u2, 0x07060302u);
        bP[qq][G] = pk.v;
      }
    }

#pragma unroll
    for (int qq = 0; qq < 4; ++qq)
#pragma unroll
      for (int G = 0; G < 2; ++G)
        l_acc[qq] = __builtin_amdgcn_mfma_f32_16x16x32_bf16(aOnes, bP[qq][G], l_acc[qq], 0, 0, 0);

#pragma unroll
    for (int dt = 0; dt < 4; ++dt) {
      const unsigned short* vbase = Vs + (dt * 16 + l16) * 64;
#pragma unroll
      for (int G = 0; G < 2; ++G) {
        bf16x8 aV = *(const bf16x8*)(vbase + (((G * 4 + quad) ^ gl) << 3));
#pragma unroll
        for (int qq = 0; qq < 4; ++qq)
          o_acc[qq][dt] = __builtin_amdgcn_mfma_f32_16x16x32_bf16(aV, bP[qq][G], o_acc[qq][dt], 0, 0, 0);
      }
    }

    __builtin_amdgcn_s_setprio(0);
  }

  // ---- cross-pair combine via LDS
  __syncthreads();
  float* xf = (float*)SH;
  if (kp == 1) {
    float* dst = xf + (size_t)(wq * 64 + lane) * 68;
#pragma unroll
    for (int qq = 0; qq < 4; ++qq)
#pragma unroll
      for (int dt = 0; dt < 4; ++dt)
        *(f32x4*)(dst + qq * 16 + dt * 4) = o_acc[qq][dt];
    f32x4 lv = {l_acc[0][0], l_acc[1][0], l_acc[2][0], l_acc[3][0]};
    *(f32x4*)(dst + 64) = lv;
  }
  __syncthreads();
  if (kp == 0) {
    const float* src = xf + (size_t)(wq * 64 + lane) * 68;
#pragma unroll
    for (int qq = 0; qq < 4; ++qq)
#pragma unroll
      for (int dt = 0; dt < 4; ++dt)
        o_acc[qq][dt] += *(const f32x4*)(src + qq * 16 + dt * 4);
    const f32x4 lv = *(const f32x4*)(src + 64);

    const int b = bh >> 4, h = bh & 15;
#pragma unroll
    for (int qq = 0; qq < 4; ++qq) {
      const int qg = q0 + wq * 64 + qq * 16 + l16;
      const float inv = 1.0f / (l_acc[qq][0] + lv[qq]);
      const unsigned short* vp = Vp + qg;
      float ov = 0.f, v2 = 0.f;
#pragma unroll
      for (int dt = 0; dt < 4; ++dt)
#pragma unroll
        for (int r = 0; r < 4; ++r) {
          const int d = dt * 16 + quad * 4 + r;
          const float v = bf2f(vp[(size_t)d * SEQ]);
          ov += o_acc[qq][dt][r] * v;
          v2 += v * v;
        }
      ov *= inv;
      ov += __shfl_xor(ov, 16); ov += __shfl_xor(ov, 32);
      v2 += __shfl_xor(v2, 16); v2 += __shfl_xor(v2, 32);
      const float align = ov / (v2 + 1e-8f);
      unsigned short* dst = O + (size_t)(b * SEQ + qg) * DM + h * 64;
#pragma unroll
      for (int dt = 0; dt < 4; ++dt) {
        float a[4];
#pragma unroll
        for (int r = 0; r < 4; ++r) {
          const int d = dt * 16 + quad * 4 + r;
          const float v = bf2f(vp[(size_t)d * SEQ]);
          a[r] = __builtin_fmaf(o_acc[qq][dt][r], inv, -align * v);
        }
        uint2 pk2;
        pk2.x = pkbf(a[0], a[1]);
        pk2.y = pkbf(a[2], a[3]);
        *(uint2*)(dst + dt * 16 + quad * 4) = pk2;
      }
    }
  }
#undef KKB
#undef VVB
}

// out = O @ Wo^T + bo, fp32 output.
// R11: back to 64x128 tiles / gemm_pipe<2> / 512 blocks = 2 blk/CU =
// 2 waves/SIMD. R5's 128^2 x 256-block config ran at 1 wave/SIMD -- the
// occupancy level R9 measured as a 1.7x cliff. Trade 1.5x stage bytes
// for 2x TLP + cross-block barrier decoupling.
__global__ __launch_bounds__(256) void out_gemm(
    const unsigned short* __restrict__ Ob, const unsigned short* __restrict__ wob,
    const float* __restrict__ bo, float* __restrict__ out) {
  __shared__ unsigned short As[3 * 64 * 32], Bs[3 * 128 * 32];   // 36 KB
  const int m0 = blockIdx.y * 64, n0 = blockIdx.x * 128;
  f32x4 acc[2][4];
#pragma unroll
  for (int i = 0; i < 2; ++i)
#pragma unroll
    for (int j = 0; j < 4; ++j) { f32x4 z = {0.f, 0.f, 0.f, 0.f}; acc[i][j] = z; }

  gemm_pipe<2>(Ob, wob, m0, n0, acc, As, Bs);

  const int lane = threadIdx.x & 63, w = threadIdx.x >> 6;
  const int quad = lane >> 4, l16 = lane & 15;
  const int wm = (w >> 1) * 32, wn = (w & 1) * 64;
#pragma unroll
  for (int i = 0; i < 2; ++i)
#pragma unroll
    for (int j = 0; j < 4; ++j) {
      const int col = n0 + wn + j * 16 + l16;
      const float bb = bo[col];
#pragma unroll
      for (int r = 0; r < 4; ++r) {
        const int m = m0 + wm + i * 16 + quad * 4 + r;
        out[(size_t)m * DM + col] = acc[i][j][r] + bb;
      }
    }
}

extern "C" void kernel_launch(void* const* d_in, const int* in_sizes, int n_in,
                              void* d_out, int out_size, void* d_ws, size_t ws_size,
                              hipStream_t stream) {
  const float* x  = (const float*)d_in[0];
  const float* wq = (const float*)d_in[1];
  const float* bq = (const float*)d_in[2];
  const float* wk = (const float*)d_in[3];
  const float* bk = (const float*)d_in[4];
  const float* wv = (const float*)d_in[5];
  const float* bv = (const float*)d_in[6];
  const float* wo = (const float*)d_in[7];
  const float* bo = (const float*)d_in[8];
  float* out = (float*)d_out;
  (void)in_sizes; (void)n_in; (void)out_size; (void)ws_size;

  unsigned short* ws  = (unsigned short*)d_ws;
  unsigned short* xb  = ws;                         // 4096*1024
  unsigned short* wqb = xb + (size_t)NTOK * DM;     // 1024*1024 each (contiguous!)
  unsigned short* wkb = wqb + (size_t)DM * DM;
  unsigned short* wvb = wkb + (size_t)DM * DM;
  unsigned short* wob = wvb + (size_t)DM * DM;
  unsigned short* Qb  = wob + (size_t)DM * DM;      // [32][2048][64]
  unsigned short* Kb  = Qb + (size_t)NTOK * DM;
  unsigned short* Vtb = Kb + (size_t)NTOK * DM;     // [32][64][2048]
  unsigned short* Ob  = Vtb + (size_t)NTOK * DM;    // [4096][1024]

  cast_all<<<8192, 256, 0, stream>>>(x, wq, wk, wv, wo, ws);
  qkv_gemm<<<512, 256, 0, stream>>>(xb, wqb, wkb, wvb, bq, bk, bv, Qb, Kb, Vtb);
  attn_kernel<<<512, 256, 0, stream>>>(Qb, Kb, Vtb, Ob);
  out_gemm<<<dim3(8, 64), 256, 0, stream>>>(Ob, wob, bo, out);
}